// Round 4
// baseline (630.639 us; speedup 1.0000x reference)
//
#include <hip/hip_runtime.h>
#include <hip/hip_bf16.h>

#define H 16
#define D 24
#define DS 384
#define CZ 128
#define S 512
#define EPSV 1e-5f

typedef unsigned int u32;
typedef unsigned short u16;

__device__ __forceinline__ float bf2f(u16 u) { return __uint_as_float(((u32)u) << 16); }
__device__ __forceinline__ float bf_lo(u32 u) { return __uint_as_float(u << 16); }
__device__ __forceinline__ float bf_hi(u32 u) { return __uint_as_float(u & 0xffff0000u); }
__device__ __forceinline__ float ldany(const void* p, long i, bool isb) {
    return isb ? bf2f(((const u16*)p)[i]) : ((const float*)p)[i];
}

// ---------------- Kernel 0: dtype sniffing ----------------
// z_ln_w is exactly ones. First u32: bf16 pair -> 0x3F803F80, fp32 -> 0x3F800000.
__global__ void flag_kernel(const void* __restrict__ z_ln_w, int* __restrict__ flag)
{
    if (threadIdx.x == 0 && blockIdx.x == 0) {
        u32 w = *(const u32*)z_ln_w;
        flag[0] = (w == 0x3F800000u) ? 0 : 1;   // 1 => bf16 inputs
    }
}

// ---------------- Kernel 1: fused Q/K/V/Gate projections ----------------
__global__ __launch_bounds__(256) void proj_kernel(
    const void* __restrict__ s, const void* __restrict__ q_w, const void* __restrict__ q_b,
    const void* __restrict__ k_w, const void* __restrict__ v_w, const void* __restrict__ g_w,
    const int* __restrict__ flag, float* __restrict__ wsb)
{
    const bool isb = (flag[0] != 0);
    int idx = blockIdx.x * 256 + threadIdx.x;        // 0 .. 4*S*DS
    int which = idx / (S * DS);
    int rem = idx - which * (S * DS);
    int r = rem / DS;
    int c = rem - r * DS;
    const void* w = (which == 0) ? q_w : (which == 1) ? k_w : (which == 2) ? v_w : g_w;
    float acc = 0.f;
    if (isb) {
        const u16* sp = (const u16*)s + r * DS;
        const u16* wp = (const u16*)w + c * DS;
        for (int k = 0; k < DS; ++k) acc += bf2f(sp[k]) * bf2f(wp[k]);
    } else {
        const float4* sp = reinterpret_cast<const float4*>((const float*)s + r * DS);
        const float4* wp = reinterpret_cast<const float4*>((const float*)w + c * DS);
#pragma unroll 4
        for (int k = 0; k < DS / 4; ++k) {
            float4 av = sp[k];
            float4 bv = wp[k];
            acc += av.x * bv.x + av.y * bv.y + av.z * bv.z + av.w * bv.w;
        }
    }
    if (which == 0) acc += ldany(q_b, c, isb);
    if (which == 3) acc = 1.f / (1.f + __expf(-acc));
    wsb[idx] = acc;   // Q | K | V | G contiguous fp32
}

// ---------------- Kernel 2: fused pair-bias + attention + gating ----------------
// One block (4 waves) per query row q. lane = cg*16 + h (cg: 32-ch chunk, h: head).
// LN(z)@z_w folded: bias = rstd*dot(z,a) - mu*rstd*A + B.
__global__ __launch_bounds__(256) void attn_kernel(
    const void* __restrict__ z, const void* __restrict__ seq_mask,
    const void* __restrict__ z_ln_w, const void* __restrict__ z_ln_b,
    const void* __restrict__ z_w,
    const int* __restrict__ flag,
    const float* __restrict__ wsb, float* __restrict__ og)
{
    const bool isb = (flag[0] != 0);
    const float* Q = wsb;
    const float* K = wsb + S * DS;
    const float* V = wsb + 2 * S * DS;
    const float* G = wsb + 3 * S * DS;

    const int q = blockIdx.x;
    const int tid = threadIdx.x;
    const int wave = tid >> 6;
    const int lane = tid & 63;
    const int cg = lane >> 4;
    const int h = lane & 15;
    const int c0 = cg * 32;

    __shared__ float sc[H][S + 1];
    __shared__ float inv_l[H];

    // folded LN+proj constants
    float a[32];
    float A = 0.f, Bc = 0.f;
#pragma unroll
    for (int e = 0; e < 32; ++e) {
        int c = c0 + e;
        float lw = ldany(z_ln_w, c, isb);
        float lb = ldany(z_ln_b, c, isb);
        float zw = ldany(z_w, h * CZ + c, isb);
        a[e] = lw * zw;
        A += a[e];
        Bc += lb * zw;
    }
    A += __shfl_xor(A, 16);   A += __shfl_xor(A, 32);
    Bc += __shfl_xor(Bc, 16); Bc += __shfl_xor(Bc, 32);

    float qreg[6];
#pragma unroll
    for (int i = 0; i < 6; ++i) qreg[i] = Q[q * DS + h * D + cg * 6 + i];

    const float scale = 0.2041241452319315f;  // 1/sqrt(24)

    for (int j = wave; j < S; j += 4) {
        float zv[32];
        long zoff = ((long)(q * S + j)) * CZ + c0;
        if (isb) {
            const uint4* zp = reinterpret_cast<const uint4*>((const u16*)z + zoff);
#pragma unroll
            for (int t = 0; t < 4; ++t) {
                uint4 u = zp[t];
                zv[t * 8 + 0] = bf_lo(u.x); zv[t * 8 + 1] = bf_hi(u.x);
                zv[t * 8 + 2] = bf_lo(u.y); zv[t * 8 + 3] = bf_hi(u.y);
                zv[t * 8 + 4] = bf_lo(u.z); zv[t * 8 + 5] = bf_hi(u.z);
                zv[t * 8 + 6] = bf_lo(u.w); zv[t * 8 + 7] = bf_hi(u.w);
            }
        } else {
            const float4* zp = reinterpret_cast<const float4*>((const float*)z + zoff);
#pragma unroll
            for (int t = 0; t < 8; ++t) {
                float4 f = zp[t];
                zv[t * 4 + 0] = f.x; zv[t * 4 + 1] = f.y;
                zv[t * 4 + 2] = f.z; zv[t * 4 + 3] = f.w;
            }
        }
        float sum = 0.f, sq = 0.f, dza = 0.f;
#pragma unroll
        for (int e = 0; e < 32; ++e) {
            float f = zv[e];
            sum += f;
            sq += f * f;
            dza += f * a[e];
        }
        sum += __shfl_xor(sum, 16); sum += __shfl_xor(sum, 32);
        sq  += __shfl_xor(sq, 16);  sq  += __shfl_xor(sq, 32);
        dza += __shfl_xor(dza, 16); dza += __shfl_xor(dza, 32);
        float mu = sum * (1.f / 128.f);
        float var = sq * (1.f / 128.f) - mu * mu;
        float rstd = 1.f / sqrtf(var + EPSV);
        float bias = rstd * dza - mu * rstd * A + Bc;

        const float* krow = K + j * DS + h * D + cg * 6;
        float pk = qreg[0] * krow[0] + qreg[1] * krow[1] + qreg[2] * krow[2]
                 + qreg[3] * krow[3] + qreg[4] * krow[4] + qreg[5] * krow[5];
        pk += __shfl_xor(pk, 16); pk += __shfl_xor(pk, 32);

        float score = pk * scale + bias + ldany(seq_mask, j, isb);
        if (cg == 0) sc[h][j] = score;
    }
    __syncthreads();

    // softmax: team of 16 threads per head
    {
        int hh = tid >> 4;
        int ti = tid & 15;
        float m = -1e30f;
        for (int j = ti; j < S; j += 16) m = fmaxf(m, sc[hh][j]);
#pragma unroll
        for (int mk = 1; mk < 16; mk <<= 1) m = fmaxf(m, __shfl_xor(m, mk, 16));
        float sum = 0.f;
        for (int j = ti; j < S; j += 16) {
            float p = __expf(sc[hh][j] - m);
            sc[hh][j] = p;
            sum += p;
        }
#pragma unroll
        for (int mk = 1; mk < 16; mk <<= 1) sum += __shfl_xor(sum, mk, 16);
        if (ti == 0) inv_l[hh] = 1.f / sum;
    }
    __syncthreads();

    for (int idx = tid; idx < DS; idx += 256) {
        int h2 = idx / D;
        float acc = 0.f;
#pragma unroll 4
        for (int j = 0; j < S; ++j) acc += sc[h2][j] * V[j * DS + idx];
        og[q * DS + idx] = acc * inv_l[h2] * G[q * DS + idx];
    }
}

// ---------------- Kernel 3: output projection -> fp32 ----------------
__global__ __launch_bounds__(256) void out_kernel(
    const float* __restrict__ og, const void* __restrict__ o_w,
    const int* __restrict__ flag, float* __restrict__ out)
{
    const bool isb = (flag[0] != 0);
    int idx = blockIdx.x * 256 + threadIdx.x;
    int r = idx / DS;
    int c = idx - r * DS;
    float acc = 0.f;
    if (isb) {
        const float* op = og + r * DS;
        const u16* wp = (const u16*)o_w + c * DS;
        for (int k = 0; k < DS; ++k) acc += op[k] * bf2f(wp[k]);
    } else {
        const float4* op = reinterpret_cast<const float4*>(og + r * DS);
        const float4* wp = reinterpret_cast<const float4*>((const float*)o_w + c * DS);
#pragma unroll 4
        for (int k = 0; k < DS / 4; ++k) {
            float4 w = wp[k];
            float4 o = op[k];
            acc += o.x * w.x + o.y * w.y + o.z * w.z + o.w * w.w;
        }
    }
    out[idx] = acc;   // fp32 output (reference output dtype)
}

extern "C" void kernel_launch(void* const* d_in, const int* in_sizes, int n_in,
                              void* d_out, int out_size, void* d_ws, size_t ws_size,
                              hipStream_t stream)
{
    const void* s      = d_in[0];
    const void* z      = d_in[1];
    const void* mask   = d_in[2];
    const void* q_w    = d_in[3];
    const void* q_b    = d_in[4];
    const void* k_w    = d_in[5];
    const void* v_w    = d_in[6];
    const void* g_w    = d_in[7];
    const void* o_w    = d_in[8];
    const void* z_ln_w = d_in[9];
    const void* z_ln_b = d_in[10];
    const void* z_w    = d_in[11];

    int* flag = (int*)d_ws;                    // flag first
    float* wsb = (float*)d_ws + 16;            // Q | K | V | G (each S*DS fp32)
    float* og = wsb + 4 * S * DS;              // S*DS fp32

    hipLaunchKernelGGL(flag_kernel, dim3(1), dim3(64), 0, stream, z_ln_w, flag);
    hipLaunchKernelGGL(proj_kernel, dim3(4 * S * DS / 256), dim3(256), 0, stream,
                       s, q_w, q_b, k_w, v_w, g_w, flag, wsb);
    hipLaunchKernelGGL(attn_kernel, dim3(S), dim3(256), 0, stream,
                       z, mask, z_ln_w, z_ln_b, z_w, flag, wsb, og);
    hipLaunchKernelGGL(out_kernel, dim3(S * DS / 256), dim3(256), 0, stream,
                       og, o_w, flag, (float*)d_out);
}

// Round 5
// 609.019 us; speedup vs baseline: 1.0355x; 1.0355x over previous
//
#include <hip/hip_runtime.h>

#define H 16
#define D 24
#define DS 384
#define CZ 128
#define S 512
#define EPSV 1e-5f

// ================= Kernel 1: tiled Q/K/VT/G projections =================
// grid = 4 mats x 8 row-tiles x 6 col-tiles = 192 blocks, 256 threads.
// 64x64 tile, K-chunks of 32, LDS layout [k][r] (pad 68) for b128 frag reads.
__global__ __launch_bounds__(256) void proj_kernel(
    const float* __restrict__ s, const float* __restrict__ q_w, const float* __restrict__ q_b,
    const float* __restrict__ k_w, const float* __restrict__ v_w, const float* __restrict__ g_w,
    float* __restrict__ Q, float* __restrict__ K, float* __restrict__ VT, float* __restrict__ G)
{
    const int b = blockIdx.x;
    const int mat = b / 48;          // 0:Q 1:K 2:V 3:G
    const int t = b % 48;
    const int by = t / 6, bx = t % 6;
    const float* w = (mat == 0) ? q_w : (mat == 1) ? k_w : (mat == 2) ? v_w : g_w;

    __shared__ float As[32][68];     // [k][row]
    __shared__ float Ws[32][68];     // [k][col]

    const int tid = threadIdx.x;
    const int tx = tid & 15, ty = tid >> 4;
    const int r8 = tid >> 3;         // 0..31
    const int c4 = tid & 7;          // 0..7  (float4 col within 32-k chunk)

    float acc[4][4] = {};
    for (int kc = 0; kc < DS; kc += 32) {
        __syncthreads();
#pragma unroll
        for (int pass = 0; pass < 2; ++pass) {
            int r = r8 + pass * 32;
            float4 sv = *(const float4*)(s + (by * 64 + r) * DS + kc + c4 * 4);
            float4 wv = *(const float4*)(w + (bx * 64 + r) * DS + kc + c4 * 4);
            As[c4 * 4 + 0][r] = sv.x; As[c4 * 4 + 1][r] = sv.y;
            As[c4 * 4 + 2][r] = sv.z; As[c4 * 4 + 3][r] = sv.w;
            Ws[c4 * 4 + 0][r] = wv.x; Ws[c4 * 4 + 1][r] = wv.y;
            Ws[c4 * 4 + 2][r] = wv.z; Ws[c4 * 4 + 3][r] = wv.w;
        }
        __syncthreads();
#pragma unroll
        for (int k = 0; k < 32; ++k) {
            float4 a4 = *(const float4*)&As[k][ty * 4];
            float4 b4 = *(const float4*)&Ws[k][tx * 4];
            acc[0][0] += a4.x * b4.x; acc[0][1] += a4.x * b4.y; acc[0][2] += a4.x * b4.z; acc[0][3] += a4.x * b4.w;
            acc[1][0] += a4.y * b4.x; acc[1][1] += a4.y * b4.y; acc[1][2] += a4.y * b4.z; acc[1][3] += a4.y * b4.w;
            acc[2][0] += a4.z * b4.x; acc[2][1] += a4.z * b4.y; acc[2][2] += a4.z * b4.z; acc[2][3] += a4.z * b4.w;
            acc[3][0] += a4.w * b4.x; acc[3][1] += a4.w * b4.y; acc[3][2] += a4.w * b4.z; acc[3][3] += a4.w * b4.w;
        }
    }

    const int r0 = by * 64 + ty * 4;
    const int c0 = bx * 64 + tx * 4;
    if (mat == 2) {
        // V transposed: VT[c][r]
#pragma unroll
        for (int ii = 0; ii < 4; ++ii)
#pragma unroll
            for (int jj = 0; jj < 4; ++jj)
                VT[(c0 + jj) * S + (r0 + ii)] = acc[ii][jj];
    } else {
        float* dst = (mat == 0) ? Q : (mat == 1) ? K : G;
#pragma unroll
        for (int ii = 0; ii < 4; ++ii) {
            float4 v;
            v.x = acc[ii][0]; v.y = acc[ii][1]; v.z = acc[ii][2]; v.w = acc[ii][3];
            if (mat == 0) {
                v.x += q_b[c0 + 0]; v.y += q_b[c0 + 1]; v.z += q_b[c0 + 2]; v.w += q_b[c0 + 3];
            } else if (mat == 3) {
                v.x = 1.f / (1.f + __expf(-v.x)); v.y = 1.f / (1.f + __expf(-v.y));
                v.z = 1.f / (1.f + __expf(-v.z)); v.w = 1.f / (1.f + __expf(-v.w));
            }
            *(float4*)(dst + (r0 + ii) * DS + c0) = v;
        }
    }
}

// ================= Kernel 2: fused bias + attention + gating =================
// One block (256 thr, 4 waves) per query row q.
// Phase A: thread-per-key-row: in-thread LN stats (no shuffles), bias dot with
// wave-uniform z_w reads (compiler -> s_load), fused QK via float4.
__global__ __launch_bounds__(256) void attn_kernel(
    const float* __restrict__ z, const float* __restrict__ seq_mask,
    const float* __restrict__ z_ln_w, const float* __restrict__ z_ln_b,
    const float* __restrict__ z_w,
    const float* __restrict__ Q, const float* __restrict__ K,
    const float* __restrict__ VT, const float* __restrict__ G,
    float* __restrict__ og)
{
    const int q = blockIdx.x;
    const int tid = threadIdx.x;
    const int wv = tid >> 6;
    const int lane = tid & 63;

    __shared__ float sc[H][S + 4];     // stride 516: 16B-aligned rows, 2-way banks
    __shared__ float qrow[DS];
    __shared__ float opart[4][DS];
    __shared__ float inv_l[H];

    for (int i = tid; i < DS; i += 256) qrow[i] = Q[q * DS + i];
    __syncthreads();

    const float scale = 0.2041241452319315f;  // 1/sqrt(24)

    // ---- Phase A ----
#pragma unroll
    for (int jj = 0; jj < 2; ++jj) {
        const int j = jj * 256 + tid;
        const float4* zr = (const float4*)(z + ((long)(q * S + j)) * CZ);
        // pass 1: stats
        float sum = 0.f, sq = 0.f;
#pragma unroll
        for (int t = 0; t < 32; ++t) {
            float4 f = zr[t];
            sum += f.x + f.y + f.z + f.w;
            sq += f.x * f.x + f.y * f.y + f.z * f.z + f.w * f.w;
        }
        float mu = sum * (1.f / 128.f);
        float var = sq * (1.f / 128.f) - mu * mu;
        float rstd = 1.f / sqrtf(var + EPSV);
        // pass 2: LN + bias dot (z_w/z_ln_* indices wave-uniform -> scalar loads)
        float bias[16] = {};
#pragma unroll
        for (int t = 0; t < 32; ++t) {
            float4 f = zr[t];
            float zv[4] = { f.x, f.y, f.z, f.w };
#pragma unroll
            for (int u = 0; u < 4; ++u) {
                int c = 4 * t + u;
                float ln = (zv[u] - mu) * rstd * z_ln_w[c] + z_ln_b[c];
#pragma unroll
                for (int h = 0; h < 16; ++h) bias[h] += ln * z_w[h * CZ + c];
            }
        }
        // QK dots
        float qk[16] = {};
        const float4* kr = (const float4*)(K + j * DS);
#pragma unroll
        for (int t = 0; t < 96; ++t) {
            float4 kv = kr[t];
            float4 q4 = *(const float4*)&qrow[4 * t];
            qk[t / 6] += kv.x * q4.x + kv.y * q4.y + kv.z * q4.z + kv.w * q4.w;
        }
        float mk = seq_mask[j];
#pragma unroll
        for (int h = 0; h < 16; ++h)
            sc[h][j] = qk[h] * scale + bias[h] + mk;
    }
    __syncthreads();

    // ---- Phase B: softmax, 4 heads per wave ----
#pragma unroll
    for (int i = 0; i < 4; ++i) {
        int h = wv * 4 + i;
        float m = -1e30f;
        for (int j = lane; j < S; j += 64) m = fmaxf(m, sc[h][j]);
#pragma unroll
        for (int mk2 = 1; mk2 < 64; mk2 <<= 1) m = fmaxf(m, __shfl_xor(m, mk2));
        float sum = 0.f;
        for (int j = lane; j < S; j += 64) {
            float p = __expf(sc[h][j] - m);
            sc[h][j] = p;
            sum += p;
        }
#pragma unroll
        for (int mk2 = 1; mk2 < 64; mk2 <<= 1) sum += __shfl_xor(sum, mk2);
        if (lane == 0) inv_l[h] = 1.f / sum;
    }
    __syncthreads();

    // ---- Phase C: P @ V, j-split across waves ----
#pragma unroll
    for (int ii = 0; ii < 6; ++ii) {
        int idx = ii * 64 + lane;
        int h = idx / 24;
        float acc = 0.f;
        const float4* vt4 = (const float4*)(VT + idx * S + wv * 128);
        const float4* sc4 = (const float4*)&sc[h][wv * 128];
#pragma unroll
        for (int t = 0; t < 32; ++t) {
            float4 a = sc4[t];
            float4 b = vt4[t];
            acc += a.x * b.x + a.y * b.y + a.z * b.z + a.w * b.w;
        }
        opart[wv][idx] = acc;
    }
    __syncthreads();
    for (int i = tid; i < DS; i += 256) {
        float o = opart[0][i] + opart[1][i] + opart[2][i] + opart[3][i];
        int h = i / 24;
        og[q * DS + i] = o * inv_l[h] * G[q * DS + i];
    }
}

// ================= Kernel 3: tiled output projection =================
// out[r][c] = sum_k og[r][k] * o_w[c][k];  grid 48 blocks.
__global__ __launch_bounds__(256) void out_kernel(
    const float* __restrict__ og, const float* __restrict__ o_w, float* __restrict__ out)
{
    const int b = blockIdx.x;
    const int by = b / 6, bx = b % 6;

    __shared__ float As[32][68];
    __shared__ float Ws[32][68];

    const int tid = threadIdx.x;
    const int tx = tid & 15, ty = tid >> 4;
    const int r8 = tid >> 3;
    const int c4 = tid & 7;

    float acc[4][4] = {};
    for (int kc = 0; kc < DS; kc += 32) {
        __syncthreads();
#pragma unroll
        for (int pass = 0; pass < 2; ++pass) {
            int r = r8 + pass * 32;
            float4 sv = *(const float4*)(og + (by * 64 + r) * DS + kc + c4 * 4);
            float4 wvv = *(const float4*)(o_w + (bx * 64 + r) * DS + kc + c4 * 4);
            As[c4 * 4 + 0][r] = sv.x; As[c4 * 4 + 1][r] = sv.y;
            As[c4 * 4 + 2][r] = sv.z; As[c4 * 4 + 3][r] = sv.w;
            Ws[c4 * 4 + 0][r] = wvv.x; Ws[c4 * 4 + 1][r] = wvv.y;
            Ws[c4 * 4 + 2][r] = wvv.z; Ws[c4 * 4 + 3][r] = wvv.w;
        }
        __syncthreads();
#pragma unroll
        for (int k = 0; k < 32; ++k) {
            float4 a4 = *(const float4*)&As[k][ty * 4];
            float4 b4 = *(const float4*)&Ws[k][tx * 4];
            acc[0][0] += a4.x * b4.x; acc[0][1] += a4.x * b4.y; acc[0][2] += a4.x * b4.z; acc[0][3] += a4.x * b4.w;
            acc[1][0] += a4.y * b4.x; acc[1][1] += a4.y * b4.y; acc[1][2] += a4.y * b4.z; acc[1][3] += a4.y * b4.w;
            acc[2][0] += a4.z * b4.x; acc[2][1] += a4.z * b4.y; acc[2][2] += a4.z * b4.z; acc[2][3] += a4.z * b4.w;
            acc[3][0] += a4.w * b4.x; acc[3][1] += a4.w * b4.y; acc[3][2] += a4.w * b4.z; acc[3][3] += a4.w * b4.w;
        }
    }

    const int r0 = by * 64 + ty * 4;
    const int c0 = bx * 64 + tx * 4;
#pragma unroll
    for (int ii = 0; ii < 4; ++ii) {
        float4 v;
        v.x = acc[ii][0]; v.y = acc[ii][1]; v.z = acc[ii][2]; v.w = acc[ii][3];
        *(float4*)(out + (r0 + ii) * DS + c0) = v;
    }
}

extern "C" void kernel_launch(void* const* d_in, const int* in_sizes, int n_in,
                              void* d_out, int out_size, void* d_ws, size_t ws_size,
                              hipStream_t stream)
{
    const float* s      = (const float*)d_in[0];
    const float* z      = (const float*)d_in[1];
    const float* mask   = (const float*)d_in[2];
    const float* q_w    = (const float*)d_in[3];
    const float* q_b    = (const float*)d_in[4];
    const float* k_w    = (const float*)d_in[5];
    const float* v_w    = (const float*)d_in[6];
    const float* g_w    = (const float*)d_in[7];
    const float* o_w    = (const float*)d_in[8];
    const float* z_ln_w = (const float*)d_in[9];
    const float* z_ln_b = (const float*)d_in[10];
    const float* z_w    = (const float*)d_in[11];

    float* Q  = (float*)d_ws;
    float* K  = Q + S * DS;
    float* VT = K + S * DS;
    float* G  = VT + S * DS;
    float* og = G + S * DS;

    hipLaunchKernelGGL(proj_kernel, dim3(192), dim3(256), 0, stream,
                       s, q_w, q_b, k_w, v_w, g_w, Q, K, VT, G);
    hipLaunchKernelGGL(attn_kernel, dim3(S), dim3(256), 0, stream,
                       z, mask, z_ln_w, z_ln_b, z_w, Q, K, VT, G, og);
    hipLaunchKernelGGL(out_kernel, dim3(48), dim3(256), 0, stream,
                       og, o_w, (float*)d_out);
}

// Round 6
// 454.265 us; speedup vs baseline: 1.3883x; 1.3407x over previous
//
#include <hip/hip_runtime.h>

#define H 16
#define D 24
#define DS 384
#define CZ 128
#define S 512
#define EPSV 1e-5f

// ================= Kernel 1: tiled Q/K/VT/G projections =================
__global__ __launch_bounds__(256) void proj_kernel(
    const float* __restrict__ s, const float* __restrict__ q_w, const float* __restrict__ q_b,
    const float* __restrict__ k_w, const float* __restrict__ v_w, const float* __restrict__ g_w,
    float* __restrict__ Q, float* __restrict__ K, float* __restrict__ VT, float* __restrict__ G)
{
    const int b = blockIdx.x;
    const int mat = b / 48;          // 0:Q 1:K 2:V 3:G
    const int t = b % 48;
    const int by = t / 6, bx = t % 6;
    const float* w = (mat == 0) ? q_w : (mat == 1) ? k_w : (mat == 2) ? v_w : g_w;

    __shared__ float As[32][68];
    __shared__ float Ws[32][68];

    const int tid = threadIdx.x;
    const int tx = tid & 15, ty = tid >> 4;
    const int r8 = tid >> 3;
    const int c4 = tid & 7;

    float acc[4][4] = {};
    for (int kc = 0; kc < DS; kc += 32) {
        __syncthreads();
#pragma unroll
        for (int pass = 0; pass < 2; ++pass) {
            int r = r8 + pass * 32;
            float4 sv = *(const float4*)(s + (by * 64 + r) * DS + kc + c4 * 4);
            float4 wv = *(const float4*)(w + (bx * 64 + r) * DS + kc + c4 * 4);
            As[c4 * 4 + 0][r] = sv.x; As[c4 * 4 + 1][r] = sv.y;
            As[c4 * 4 + 2][r] = sv.z; As[c4 * 4 + 3][r] = sv.w;
            Ws[c4 * 4 + 0][r] = wv.x; Ws[c4 * 4 + 1][r] = wv.y;
            Ws[c4 * 4 + 2][r] = wv.z; Ws[c4 * 4 + 3][r] = wv.w;
        }
        __syncthreads();
#pragma unroll
        for (int k = 0; k < 32; ++k) {
            float4 a4 = *(const float4*)&As[k][ty * 4];
            float4 b4 = *(const float4*)&Ws[k][tx * 4];
            acc[0][0] += a4.x * b4.x; acc[0][1] += a4.x * b4.y; acc[0][2] += a4.x * b4.z; acc[0][3] += a4.x * b4.w;
            acc[1][0] += a4.y * b4.x; acc[1][1] += a4.y * b4.y; acc[1][2] += a4.y * b4.z; acc[1][3] += a4.y * b4.w;
            acc[2][0] += a4.z * b4.x; acc[2][1] += a4.z * b4.y; acc[2][2] += a4.z * b4.z; acc[2][3] += a4.z * b4.w;
            acc[3][0] += a4.w * b4.x; acc[3][1] += a4.w * b4.y; acc[3][2] += a4.w * b4.z; acc[3][3] += a4.w * b4.w;
        }
    }

    const int r0 = by * 64 + ty * 4;
    const int c0 = bx * 64 + tx * 4;
    if (mat == 2) {
#pragma unroll
        for (int ii = 0; ii < 4; ++ii)
#pragma unroll
            for (int jj = 0; jj < 4; ++jj)
                VT[(c0 + jj) * S + (r0 + ii)] = acc[ii][jj];
    } else {
        float* dst = (mat == 0) ? Q : (mat == 1) ? K : G;
#pragma unroll
        for (int ii = 0; ii < 4; ++ii) {
            float4 v;
            v.x = acc[ii][0]; v.y = acc[ii][1]; v.z = acc[ii][2]; v.w = acc[ii][3];
            if (mat == 0) {
                v.x += q_b[c0 + 0]; v.y += q_b[c0 + 1]; v.z += q_b[c0 + 2]; v.w += q_b[c0 + 3];
            } else if (mat == 3) {
                v.x = 1.f / (1.f + __expf(-v.x)); v.y = 1.f / (1.f + __expf(-v.y));
                v.z = 1.f / (1.f + __expf(-v.z)); v.w = 1.f / (1.f + __expf(-v.w));
            }
            *(float4*)(dst + (r0 + ii) * DS + c0) = v;
        }
    }
}

// ================= Kernel 2a: fused LN+bias+QK scores =================
// grid 2048: b = q*4 + jt. Wave-per-key-row, lane = cg*16 + h. No big LDS.
__global__ __launch_bounds__(256) void score_kernel(
    const float* __restrict__ z, const float* __restrict__ seq_mask,
    const float* __restrict__ z_ln_w, const float* __restrict__ z_ln_b,
    const float* __restrict__ z_w,
    const float* __restrict__ Q, const float* __restrict__ K,
    float* __restrict__ scores)
{
    const int b = blockIdx.x;
    const int q = b >> 2;
    const int jt = b & 3;
    const int tid = threadIdx.x;
    const int wv = tid >> 6;
    const int lane = tid & 63;
    const int cg = lane >> 4;
    const int h = lane & 15;
    const int c0 = cg * 32;

    float a[32];
    float A = 0.f, Bc = 0.f;
#pragma unroll
    for (int e = 0; e < 32; ++e) {
        int c = c0 + e;
        float zw = z_w[h * CZ + c];
        a[e] = z_ln_w[c] * zw;
        A += a[e];
        Bc += z_ln_b[c] * zw;
    }
    A += __shfl_xor(A, 16);   A += __shfl_xor(A, 32);
    Bc += __shfl_xor(Bc, 16); Bc += __shfl_xor(Bc, 32);

    float qreg[6];
#pragma unroll
    for (int i = 0; i < 6; ++i) qreg[i] = Q[q * DS + h * D + cg * 6 + i];

    const float scale = 0.2041241452319315f;  // 1/sqrt(24)

#pragma unroll 2
    for (int i = 0; i < 32; ++i) {
        const int j = jt * 128 + i * 4 + wv;
        const float4* zp = (const float4*)(z + ((long)q * S + j) * CZ + c0);
        float sum = 0.f, sq = 0.f, dza = 0.f;
#pragma unroll
        for (int t = 0; t < 8; ++t) {
            float4 f = zp[t];
            sum += f.x + f.y + f.z + f.w;
            sq += f.x * f.x + f.y * f.y + f.z * f.z + f.w * f.w;
            dza += f.x * a[4 * t] + f.y * a[4 * t + 1] + f.z * a[4 * t + 2] + f.w * a[4 * t + 3];
        }
        sum += __shfl_xor(sum, 16); sum += __shfl_xor(sum, 32);
        sq  += __shfl_xor(sq, 16);  sq  += __shfl_xor(sq, 32);
        dza += __shfl_xor(dza, 16); dza += __shfl_xor(dza, 32);
        float mu = sum * (1.f / 128.f);
        float var = sq * (1.f / 128.f) - mu * mu;
        float rstd = 1.f / sqrtf(var + EPSV);
        float bias = rstd * dza - mu * rstd * A + Bc;

        const float* kr = K + j * DS + h * D + cg * 6;
        float pk = qreg[0] * kr[0] + qreg[1] * kr[1] + qreg[2] * kr[2]
                 + qreg[3] * kr[3] + qreg[4] * kr[4] + qreg[5] * kr[5];
        pk += __shfl_xor(pk, 16); pk += __shfl_xor(pk, 32);

        if (cg == 0)
            scores[((q << 4) + h) * S + j] = pk * scale + bias + seq_mask[j];
    }
}

// ================= Kernel 2b: softmax + PV + gate =================
__global__ __launch_bounds__(256) void spv_kernel(
    const float* __restrict__ scores, const float* __restrict__ VT,
    const float* __restrict__ G, float* __restrict__ og)
{
    const int q = blockIdx.x;
    const int tid = threadIdx.x;
    const int wv = tid >> 6;
    const int lane = tid & 63;

    __shared__ float sc[H][S + 4];
    __shared__ float opart[4][DS];
    __shared__ float inv_l[H];

    for (int i = tid; i < H * (S / 4); i += 256) {
        int row = i >> 7, f4 = i & 127;
        float4 v = ((const float4*)(scores + ((q << 4) + row) * S))[f4];
        *(float4*)&sc[row][f4 * 4] = v;
    }
    __syncthreads();

#pragma unroll
    for (int i = 0; i < 4; ++i) {
        int h = wv * 4 + i;
        float m = -1e30f;
        for (int j = lane; j < S; j += 64) m = fmaxf(m, sc[h][j]);
#pragma unroll
        for (int mk = 1; mk < 64; mk <<= 1) m = fmaxf(m, __shfl_xor(m, mk));
        float sum = 0.f;
        for (int j = lane; j < S; j += 64) {
            float p = __expf(sc[h][j] - m);
            sc[h][j] = p;
            sum += p;
        }
#pragma unroll
        for (int mk = 1; mk < 64; mk <<= 1) sum += __shfl_xor(sum, mk);
        if (lane == 0) inv_l[h] = 1.f / sum;
    }
    __syncthreads();

#pragma unroll
    for (int ii = 0; ii < 6; ++ii) {
        int idx = ii * 64 + lane;
        int h = idx / 24;
        float acc = 0.f;
        const float4* vt4 = (const float4*)(VT + idx * S + wv * 128);
        const float4* sc4 = (const float4*)&sc[h][wv * 128];
#pragma unroll
        for (int t = 0; t < 32; ++t) {
            float4 p = sc4[t];
            float4 v = vt4[t];
            acc += p.x * v.x + p.y * v.y + p.z * v.z + p.w * v.w;
        }
        opart[wv][idx] = acc;
    }
    __syncthreads();
    for (int i = tid; i < DS; i += 256) {
        float o = opart[0][i] + opart[1][i] + opart[2][i] + opart[3][i];
        int h = i / 24;
        og[q * DS + i] = o * inv_l[h] * G[q * DS + i];
    }
}

// ================= Fallback: fused attn (if ws too small for scores) =================
__global__ __launch_bounds__(256) void attn_fused_kernel(
    const float* __restrict__ z, const float* __restrict__ seq_mask,
    const float* __restrict__ z_ln_w, const float* __restrict__ z_ln_b,
    const float* __restrict__ z_w,
    const float* __restrict__ Q, const float* __restrict__ K,
    const float* __restrict__ VT, const float* __restrict__ G,
    float* __restrict__ og)
{
    const int q = blockIdx.x;
    const int tid = threadIdx.x;
    const int wv = tid >> 6;
    const int lane = tid & 63;
    const int cg = lane >> 4;
    const int h = lane & 15;
    const int c0 = cg * 32;

    __shared__ float sc[H][S + 4];
    __shared__ float opart[4][DS];
    __shared__ float inv_l[H];

    float a[32];
    float A = 0.f, Bc = 0.f;
#pragma unroll
    for (int e = 0; e < 32; ++e) {
        int c = c0 + e;
        float zw = z_w[h * CZ + c];
        a[e] = z_ln_w[c] * zw;
        A += a[e];
        Bc += z_ln_b[c] * zw;
    }
    A += __shfl_xor(A, 16);   A += __shfl_xor(A, 32);
    Bc += __shfl_xor(Bc, 16); Bc += __shfl_xor(Bc, 32);

    float qreg[6];
#pragma unroll
    for (int i = 0; i < 6; ++i) qreg[i] = Q[q * DS + h * D + cg * 6 + i];

    const float scale = 0.2041241452319315f;

    for (int j = wv; j < S; j += 4) {
        const float4* zp = (const float4*)(z + ((long)q * S + j) * CZ + c0);
        float sum = 0.f, sq = 0.f, dza = 0.f;
#pragma unroll
        for (int t = 0; t < 8; ++t) {
            float4 f = zp[t];
            sum += f.x + f.y + f.z + f.w;
            sq += f.x * f.x + f.y * f.y + f.z * f.z + f.w * f.w;
            dza += f.x * a[4 * t] + f.y * a[4 * t + 1] + f.z * a[4 * t + 2] + f.w * a[4 * t + 3];
        }
        sum += __shfl_xor(sum, 16); sum += __shfl_xor(sum, 32);
        sq  += __shfl_xor(sq, 16);  sq  += __shfl_xor(sq, 32);
        dza += __shfl_xor(dza, 16); dza += __shfl_xor(dza, 32);
        float mu = sum * (1.f / 128.f);
        float var = sq * (1.f / 128.f) - mu * mu;
        float rstd = 1.f / sqrtf(var + EPSV);
        float bias = rstd * dza - mu * rstd * A + Bc;

        const float* kr = K + j * DS + h * D + cg * 6;
        float pk = qreg[0] * kr[0] + qreg[1] * kr[1] + qreg[2] * kr[2]
                 + qreg[3] * kr[3] + qreg[4] * kr[4] + qreg[5] * kr[5];
        pk += __shfl_xor(pk, 16); pk += __shfl_xor(pk, 32);

        if (cg == 0) sc[h][j] = pk * scale + bias + seq_mask[j];
    }
    __syncthreads();

#pragma unroll
    for (int i = 0; i < 4; ++i) {
        int hh = wv * 4 + i;
        float m = -1e30f;
        for (int j = lane; j < S; j += 64) m = fmaxf(m, sc[hh][j]);
#pragma unroll
        for (int mk = 1; mk < 64; mk <<= 1) m = fmaxf(m, __shfl_xor(m, mk));
        float sum = 0.f;
        for (int j = lane; j < S; j += 64) {
            float p = __expf(sc[hh][j] - m);
            sc[hh][j] = p;
            sum += p;
        }
#pragma unroll
        for (int mk = 1; mk < 64; mk <<= 1) sum += __shfl_xor(sum, mk);
        if (lane == 0) inv_l[hh] = 1.f / sum;
    }
    __syncthreads();

#pragma unroll
    for (int ii = 0; ii < 6; ++ii) {
        int idx = ii * 64 + lane;
        int hh = idx / 24;
        float acc = 0.f;
        const float4* vt4 = (const float4*)(VT + idx * S + wv * 128);
        const float4* sc4 = (const float4*)&sc[hh][wv * 128];
#pragma unroll
        for (int t = 0; t < 32; ++t) {
            float4 p = sc4[t];
            float4 v = vt4[t];
            acc += p.x * v.x + p.y * v.y + p.z * v.z + p.w * v.w;
        }
        opart[wv][idx] = acc;
    }
    __syncthreads();
    for (int i = tid; i < DS; i += 256) {
        float o = opart[0][i] + opart[1][i] + opart[2][i] + opart[3][i];
        int hh = i / 24;
        og[q * DS + i] = o * inv_l[hh] * G[q * DS + i];
    }
}

// ================= Kernel 3: tiled output projection =================
__global__ __launch_bounds__(256) void out_kernel(
    const float* __restrict__ og, const float* __restrict__ o_w, float* __restrict__ out)
{
    const int b = blockIdx.x;
    const int by = b / 6, bx = b % 6;

    __shared__ float As[32][68];
    __shared__ float Ws[32][68];

    const int tid = threadIdx.x;
    const int tx = tid & 15, ty = tid >> 4;
    const int r8 = tid >> 3;
    const int c4 = tid & 7;

    float acc[4][4] = {};
    for (int kc = 0; kc < DS; kc += 32) {
        __syncthreads();
#pragma unroll
        for (int pass = 0; pass < 2; ++pass) {
            int r = r8 + pass * 32;
            float4 sv = *(const float4*)(og + (by * 64 + r) * DS + kc + c4 * 4);
            float4 wvv = *(const float4*)(o_w + (bx * 64 + r) * DS + kc + c4 * 4);
            As[c4 * 4 + 0][r] = sv.x; As[c4 * 4 + 1][r] = sv.y;
            As[c4 * 4 + 2][r] = sv.z; As[c4 * 4 + 3][r] = sv.w;
            Ws[c4 * 4 + 0][r] = wvv.x; Ws[c4 * 4 + 1][r] = wvv.y;
            Ws[c4 * 4 + 2][r] = wvv.z; Ws[c4 * 4 + 3][r] = wvv.w;
        }
        __syncthreads();
#pragma unroll
        for (int k = 0; k < 32; ++k) {
            float4 a4 = *(const float4*)&As[k][ty * 4];
            float4 b4 = *(const float4*)&Ws[k][tx * 4];
            acc[0][0] += a4.x * b4.x; acc[0][1] += a4.x * b4.y; acc[0][2] += a4.x * b4.z; acc[0][3] += a4.x * b4.w;
            acc[1][0] += a4.y * b4.x; acc[1][1] += a4.y * b4.y; acc[1][2] += a4.y * b4.z; acc[1][3] += a4.y * b4.w;
            acc[2][0] += a4.z * b4.x; acc[2][1] += a4.z * b4.y; acc[2][2] += a4.z * b4.z; acc[2][3] += a4.z * b4.w;
            acc[3][0] += a4.w * b4.x; acc[3][1] += a4.w * b4.y; acc[3][2] += a4.w * b4.z; acc[3][3] += a4.w * b4.w;
        }
    }

    const int r0 = by * 64 + ty * 4;
    const int c0 = bx * 64 + tx * 4;
#pragma unroll
    for (int ii = 0; ii < 4; ++ii) {
        float4 v;
        v.x = acc[ii][0]; v.y = acc[ii][1]; v.z = acc[ii][2]; v.w = acc[ii][3];
        *(float4*)(out + (r0 + ii) * DS + c0) = v;
    }
}

extern "C" void kernel_launch(void* const* d_in, const int* in_sizes, int n_in,
                              void* d_out, int out_size, void* d_ws, size_t ws_size,
                              hipStream_t stream)
{
    const float* s      = (const float*)d_in[0];
    const float* z      = (const float*)d_in[1];
    const float* mask   = (const float*)d_in[2];
    const float* q_w    = (const float*)d_in[3];
    const float* q_b    = (const float*)d_in[4];
    const float* k_w    = (const float*)d_in[5];
    const float* v_w    = (const float*)d_in[6];
    const float* g_w    = (const float*)d_in[7];
    const float* o_w    = (const float*)d_in[8];
    const float* z_ln_w = (const float*)d_in[9];
    const float* z_ln_b = (const float*)d_in[10];
    const float* z_w    = (const float*)d_in[11];

    float* Q  = (float*)d_ws;
    float* K  = Q + S * DS;
    float* VT = K + S * DS;
    float* G  = VT + S * DS;
    float* og = G + S * DS;
    float* scores = og + S * DS;            // H*S*S floats = 16.8 MB

    const size_t need = (size_t)(5 * S * DS + H * S * S) * 4;

    hipLaunchKernelGGL(proj_kernel, dim3(192), dim3(256), 0, stream,
                       s, q_w, q_b, k_w, v_w, g_w, Q, K, VT, G);
    if (ws_size >= need) {
        hipLaunchKernelGGL(score_kernel, dim3(2048), dim3(256), 0, stream,
                           z, mask, z_ln_w, z_ln_b, z_w, Q, K, scores);
        hipLaunchKernelGGL(spv_kernel, dim3(S), dim3(256), 0, stream,
                           scores, VT, G, og);
    } else {
        hipLaunchKernelGGL(attn_fused_kernel, dim3(S), dim3(256), 0, stream,
                           z, mask, z_ln_w, z_ln_b, z_w, Q, K, VT, G, og);
    }
    hipLaunchKernelGGL(out_kernel, dim3(48), dim3(256), 0, stream,
                       og, o_w, (float*)d_out);
}

// Round 7
// 378.659 us; speedup vs baseline: 1.6655x; 1.1997x over previous
//
#include <hip/hip_runtime.h>

#define H 16
#define D 24
#define DS 384
#define CZ 128
#define S 512
#define EPSV 1e-5f
#define TR 64

// ================= Kernel 1: tiled Q/K/VT/G projections =================
__global__ __launch_bounds__(256) void proj_kernel(
    const float* __restrict__ s, const float* __restrict__ q_w, const float* __restrict__ q_b,
    const float* __restrict__ k_w, const float* __restrict__ v_w, const float* __restrict__ g_w,
    float* __restrict__ Q, float* __restrict__ K, float* __restrict__ VT, float* __restrict__ G)
{
    const int b = blockIdx.x;
    const int mat = b / 48;          // 0:Q 1:K 2:V 3:G
    const int t = b % 48;
    const int by = t / 6, bx = t % 6;
    const float* w = (mat == 0) ? q_w : (mat == 1) ? k_w : (mat == 2) ? v_w : g_w;

    __shared__ float As[32][68];
    __shared__ float Ws[32][68];

    const int tid = threadIdx.x;
    const int tx = tid & 15, ty = tid >> 4;
    const int r8 = tid >> 3;
    const int c4 = tid & 7;

    float acc[4][4] = {};
    for (int kc = 0; kc < DS; kc += 32) {
        __syncthreads();
#pragma unroll
        for (int pass = 0; pass < 2; ++pass) {
            int r = r8 + pass * 32;
            float4 sv = *(const float4*)(s + (by * 64 + r) * DS + kc + c4 * 4);
            float4 wv = *(const float4*)(w + (bx * 64 + r) * DS + kc + c4 * 4);
            As[c4 * 4 + 0][r] = sv.x; As[c4 * 4 + 1][r] = sv.y;
            As[c4 * 4 + 2][r] = sv.z; As[c4 * 4 + 3][r] = sv.w;
            Ws[c4 * 4 + 0][r] = wv.x; Ws[c4 * 4 + 1][r] = wv.y;
            Ws[c4 * 4 + 2][r] = wv.z; Ws[c4 * 4 + 3][r] = wv.w;
        }
        __syncthreads();
#pragma unroll
        for (int k = 0; k < 32; ++k) {
            float4 a4 = *(const float4*)&As[k][ty * 4];
            float4 b4 = *(const float4*)&Ws[k][tx * 4];
            acc[0][0] += a4.x * b4.x; acc[0][1] += a4.x * b4.y; acc[0][2] += a4.x * b4.z; acc[0][3] += a4.x * b4.w;
            acc[1][0] += a4.y * b4.x; acc[1][1] += a4.y * b4.y; acc[1][2] += a4.y * b4.z; acc[1][3] += a4.y * b4.w;
            acc[2][0] += a4.z * b4.x; acc[2][1] += a4.z * b4.y; acc[2][2] += a4.z * b4.z; acc[2][3] += a4.z * b4.w;
            acc[3][0] += a4.w * b4.x; acc[3][1] += a4.w * b4.y; acc[3][2] += a4.w * b4.z; acc[3][3] += a4.w * b4.w;
        }
    }

    const int r0 = by * 64 + ty * 4;
    const int c0 = bx * 64 + tx * 4;
    if (mat == 2) {
#pragma unroll
        for (int ii = 0; ii < 4; ++ii)
#pragma unroll
            for (int jj = 0; jj < 4; ++jj)
                VT[(c0 + jj) * S + (r0 + ii)] = acc[ii][jj];
    } else {
        float* dst = (mat == 0) ? Q : (mat == 1) ? K : G;
#pragma unroll
        for (int ii = 0; ii < 4; ++ii) {
            float4 v;
            v.x = acc[ii][0]; v.y = acc[ii][1]; v.z = acc[ii][2]; v.w = acc[ii][3];
            if (mat == 0) {
                v.x += q_b[c0 + 0]; v.y += q_b[c0 + 1]; v.z += q_b[c0 + 2]; v.w += q_b[c0 + 3];
            } else if (mat == 3) {
                v.x = 1.f / (1.f + __expf(-v.x)); v.y = 1.f / (1.f + __expf(-v.y));
                v.z = 1.f / (1.f + __expf(-v.z)); v.w = 1.f / (1.f + __expf(-v.w));
            }
            *(float4*)(dst + (r0 + ii) * DS + c0) = v;
        }
    }
}

// ================= Kernel 2a: LDS-tiled LN+bias+QK scores =================
// grid 4096: b = q*8 + jt, 64 key-rows per block. No cross-lane in hot path.
__global__ __launch_bounds__(256) void score_kernel(
    const float* __restrict__ z, const float* __restrict__ seq_mask,
    const float* __restrict__ z_ln_w, const float* __restrict__ z_ln_b,
    const float* __restrict__ z_w,
    const float* __restrict__ Q, const float* __restrict__ K,
    float* __restrict__ scores)
{
    const int b = blockIdx.x;
    const int q = b >> 3;
    const int j0 = (b & 7) * TR;
    const int tid = threadIdx.x;

    __shared__ float zs[TR][CZ + 4];     // z tile, padded
    __shared__ float a_s[H][CZ + 4];     // folded lnw*zw
    __shared__ float qrow[DS];
    __shared__ float mu_s[TR], rs_s[TR];
    __shared__ float Ah[H], Bh[H];

    // stage a_s (coalesced)
    for (int i = tid; i < H * CZ; i += 256) {
        int h = i >> 7, c = i & 127;
        a_s[h][c] = z_ln_w[c] * z_w[h * CZ + c];
    }
    // stage z tile (coalesced float4)
    {
        const float4* zg = (const float4*)(z + ((long)q * S + j0) * CZ);
        for (int i = tid; i < TR * (CZ / 4); i += 256) {
            int row = i >> 5, c4 = i & 31;
            float4 v = zg[row * 32 + c4];
            *(float4*)&zs[row][c4 * 4] = v;
        }
    }
    for (int i = tid; i < DS; i += 256) qrow[i] = Q[q * DS + i];
    __syncthreads();

    // Ah/Bh (tiny)
    if (tid < H) {
        float A = 0.f, B = 0.f;
        for (int c = 0; c < CZ; ++c) {
            A += a_s[tid][c];
            B += z_ln_b[c] * z_w[tid * CZ + c];
        }
        Ah[tid] = A; Bh[tid] = B;
    }
    // LN stats: 4 threads per row, 2 shuffles
    {
        int row = tid >> 2, qr = tid & 3;
        const float4* zr = (const float4*)&zs[row][qr * 32];
        float sum = 0.f, sq = 0.f;
#pragma unroll
        for (int t = 0; t < 8; ++t) {
            float4 f = zr[t];
            sum += f.x + f.y + f.z + f.w;
            sq += f.x * f.x + f.y * f.y + f.z * f.z + f.w * f.w;
        }
        sum += __shfl_xor(sum, 1); sum += __shfl_xor(sum, 2);
        sq  += __shfl_xor(sq, 1);  sq  += __shfl_xor(sq, 2);
        if (qr == 0) {
            float mu = sum * (1.f / 128.f);
            float var = sq * (1.f / 128.f) - mu * mu;
            mu_s[row] = mu;
            rs_s[row] = 1.f / sqrtf(var + EPSV);
        }
    }
    __syncthreads();

    // bias GEMM: thread = 2 rows x 2 heads, pure b128+FMA from LDS
    const int rg = tid >> 3;       // 0..31
    const int hg = tid & 7;        // 0..7
    const int r0 = rg * 2, h0 = hg * 2;

    float dza[2][2] = {};
#pragma unroll 8
    for (int c4 = 0; c4 < 32; ++c4) {
        float4 z0 = *(const float4*)&zs[r0][c4 * 4];
        float4 z1 = *(const float4*)&zs[r0 + 1][c4 * 4];
        float4 a0 = *(const float4*)&a_s[h0][c4 * 4];
        float4 a1 = *(const float4*)&a_s[h0 + 1][c4 * 4];
        dza[0][0] += z0.x * a0.x + z0.y * a0.y + z0.z * a0.z + z0.w * a0.w;
        dza[0][1] += z0.x * a1.x + z0.y * a1.y + z0.z * a1.z + z0.w * a1.w;
        dza[1][0] += z1.x * a0.x + z1.y * a0.y + z1.z * a0.z + z1.w * a0.w;
        dza[1][1] += z1.x * a1.x + z1.y * a1.y + z1.z * a1.z + z1.w * a1.w;
    }

    // QK dots (K L2-resident)
    float pk[2][2];
#pragma unroll
    for (int i = 0; i < 2; ++i) {
        const float* kr = K + (long)(j0 + r0 + i) * DS;
#pragma unroll
        for (int jj = 0; jj < 2; ++jj) {
            const float4* k4 = (const float4*)(kr + (h0 + jj) * D);
            const float4* q4 = (const float4*)(qrow + (h0 + jj) * D);
            float acc = 0.f;
#pragma unroll
            for (int t = 0; t < 6; ++t) {
                float4 kv = k4[t];
                float4 qv = q4[t];
                acc += kv.x * qv.x + kv.y * qv.y + kv.z * qv.z + kv.w * qv.w;
            }
            pk[i][jj] = acc;
        }
    }

    const float scale = 0.2041241452319315f;  // 1/sqrt(24)
#pragma unroll
    for (int i = 0; i < 2; ++i) {
        int j = j0 + r0 + i;
        float mu = mu_s[r0 + i], rs = rs_s[r0 + i];
        float mk = seq_mask[j];
#pragma unroll
        for (int jj = 0; jj < 2; ++jj) {
            int h = h0 + jj;
            float bias = rs * dza[i][jj] - mu * rs * Ah[h] + Bh[h];
            scores[((q << 4) + h) * S + j] = pk[i][jj] * scale + bias + mk;
        }
    }
}

// ================= Kernel 2b: softmax + PV + gate =================
__global__ __launch_bounds__(256) void spv_kernel(
    const float* __restrict__ scores, const float* __restrict__ VT,
    const float* __restrict__ G, float* __restrict__ og)
{
    const int q = blockIdx.x;
    const int tid = threadIdx.x;
    const int wv = tid >> 6;
    const int lane = tid & 63;

    __shared__ float sc[H][S + 4];
    __shared__ float opart[4][DS];
    __shared__ float inv_l[H];

    for (int i = tid; i < H * (S / 4); i += 256) {
        int row = i >> 7, f4 = i & 127;
        float4 v = ((const float4*)(scores + ((q << 4) + row) * S))[f4];
        *(float4*)&sc[row][f4 * 4] = v;
    }
    __syncthreads();

#pragma unroll
    for (int i = 0; i < 4; ++i) {
        int h = wv * 4 + i;
        float m = -1e30f;
        for (int j = lane; j < S; j += 64) m = fmaxf(m, sc[h][j]);
#pragma unroll
        for (int mk = 1; mk < 64; mk <<= 1) m = fmaxf(m, __shfl_xor(m, mk));
        float sum = 0.f;
        for (int j = lane; j < S; j += 64) {
            float p = __expf(sc[h][j] - m);
            sc[h][j] = p;
            sum += p;
        }
#pragma unroll
        for (int mk = 1; mk < 64; mk <<= 1) sum += __shfl_xor(sum, mk);
        if (lane == 0) inv_l[h] = 1.f / sum;
    }
    __syncthreads();

#pragma unroll
    for (int ii = 0; ii < 6; ++ii) {
        int idx = ii * 64 + lane;
        int h = idx / 24;
        float acc = 0.f;
        const float4* vt4 = (const float4*)(VT + idx * S + wv * 128);
        const float4* sc4 = (const float4*)&sc[h][wv * 128];
#pragma unroll
        for (int t = 0; t < 32; ++t) {
            float4 p = sc4[t];
            float4 v = vt4[t];
            acc += p.x * v.x + p.y * v.y + p.z * v.z + p.w * v.w;
        }
        opart[wv][idx] = acc;
    }
    __syncthreads();
    for (int i = tid; i < DS; i += 256) {
        float o = opart[0][i] + opart[1][i] + opart[2][i] + opart[3][i];
        int h = i / 24;
        og[q * DS + i] = o * inv_l[h] * G[q * DS + i];
    }
}

// ================= Kernel 3: tiled output projection =================
__global__ __launch_bounds__(256) void out_kernel(
    const float* __restrict__ og, const float* __restrict__ o_w, float* __restrict__ out)
{
    const int b = blockIdx.x;
    const int by = b / 6, bx = b % 6;

    __shared__ float As[32][68];
    __shared__ float Ws[32][68];

    const int tid = threadIdx.x;
    const int tx = tid & 15, ty = tid >> 4;
    const int r8 = tid >> 3;
    const int c4 = tid & 7;

    float acc[4][4] = {};
    for (int kc = 0; kc < DS; kc += 32) {
        __syncthreads();
#pragma unroll
        for (int pass = 0; pass < 2; ++pass) {
            int r = r8 + pass * 32;
            float4 sv = *(const float4*)(og + (by * 64 + r) * DS + kc + c4 * 4);
            float4 wvv = *(const float4*)(o_w + (bx * 64 + r) * DS + kc + c4 * 4);
            As[c4 * 4 + 0][r] = sv.x; As[c4 * 4 + 1][r] = sv.y;
            As[c4 * 4 + 2][r] = sv.z; As[c4 * 4 + 3][r] = sv.w;
            Ws[c4 * 4 + 0][r] = wvv.x; Ws[c4 * 4 + 1][r] = wvv.y;
            Ws[c4 * 4 + 2][r] = wvv.z; Ws[c4 * 4 + 3][r] = wvv.w;
        }
        __syncthreads();
#pragma unroll
        for (int k = 0; k < 32; ++k) {
            float4 a4 = *(const float4*)&As[k][ty * 4];
            float4 b4 = *(const float4*)&Ws[k][tx * 4];
            acc[0][0] += a4.x * b4.x; acc[0][1] += a4.x * b4.y; acc[0][2] += a4.x * b4.z; acc[0][3] += a4.x * b4.w;
            acc[1][0] += a4.y * b4.x; acc[1][1] += a4.y * b4.y; acc[1][2] += a4.y * b4.z; acc[1][3] += a4.y * b4.w;
            acc[2][0] += a4.z * b4.x; acc[2][1] += a4.z * b4.y; acc[2][2] += a4.z * b4.z; acc[2][3] += a4.z * b4.w;
            acc[3][0] += a4.w * b4.x; acc[3][1] += a4.w * b4.y; acc[3][2] += a4.w * b4.z; acc[3][3] += a4.w * b4.w;
        }
    }

    const int r0 = by * 64 + ty * 4;
    const int c0 = bx * 64 + tx * 4;
#pragma unroll
    for (int ii = 0; ii < 4; ++ii) {
        float4 v;
        v.x = acc[ii][0]; v.y = acc[ii][1]; v.z = acc[ii][2]; v.w = acc[ii][3];
        *(float4*)(out + (r0 + ii) * DS + c0) = v;
    }
}

extern "C" void kernel_launch(void* const* d_in, const int* in_sizes, int n_in,
                              void* d_out, int out_size, void* d_ws, size_t ws_size,
                              hipStream_t stream)
{
    const float* s      = (const float*)d_in[0];
    const float* z      = (const float*)d_in[1];
    const float* mask   = (const float*)d_in[2];
    const float* q_w    = (const float*)d_in[3];
    const float* q_b    = (const float*)d_in[4];
    const float* k_w    = (const float*)d_in[5];
    const float* v_w    = (const float*)d_in[6];
    const float* g_w    = (const float*)d_in[7];
    const float* o_w    = (const float*)d_in[8];
    const float* z_ln_w = (const float*)d_in[9];
    const float* z_ln_b = (const float*)d_in[10];
    const float* z_w    = (const float*)d_in[11];

    float* Q  = (float*)d_ws;
    float* K  = Q + S * DS;
    float* VT = K + S * DS;
    float* G  = VT + S * DS;
    float* og = G + S * DS;
    float* scores = og + S * DS;            // H*S*S floats = 16.8 MB

    hipLaunchKernelGGL(proj_kernel, dim3(192), dim3(256), 0, stream,
                       s, q_w, q_b, k_w, v_w, g_w, Q, K, VT, G);
    hipLaunchKernelGGL(score_kernel, dim3(4096), dim3(256), 0, stream,
                       z, mask, z_ln_w, z_ln_b, z_w, Q, K, scores);
    hipLaunchKernelGGL(spv_kernel, dim3(S), dim3(256), 0, stream,
                       scores, VT, G, og);
    hipLaunchKernelGGL(out_kernel, dim3(48), dim3(256), 0, stream,
                       og, o_w, (float*)d_out);
}